// Round 2
// baseline (13603.011 us; speedup 1.0000x reference)
//
#include <hip/hip_runtime.h>
#include <math.h>

typedef unsigned short u16;
typedef unsigned int   u32;
typedef unsigned long long u64;
typedef _Float16 f16;
typedef __attribute__((ext_vector_type(8))) _Float16 f16x8;
typedef __attribute__((ext_vector_type(4))) float    f32x4;
typedef __attribute__((ext_vector_type(4))) u32      u32x4;

#define T_SEQ 1024
#define NB    64
#define HID   512
#define KC    384       // 3*128 combined conv+Wx K
#define G4    2048      // 4*HID
#define MR    (NB*T_SEQ) // 65536
#define ZD2   128       // 2*ZD
#define WPAD  528       // LDS row stride (f16): 1056B -> 2-way bank alias (free)

// ---------------- static device buffers ----------------
__device__ __align__(16) f16   g_xwin[(size_t)MR*KC];    // 48 MB window-matrix (f16)
__device__ __align__(16) f16   g_cwxt[(size_t)G4*KC];    // combined (conv_w@Wx)^T  [n][k]
__device__              float  g_bb[G4];                 // conv_b@Wx + b
__device__ __align__(16) f16   g_whT[(size_t)G4*HID];    // Wh^T [2048][512]
__device__ __align__(16) f16   g_w1T[(size_t)HID*HID];
__device__ __align__(16) f16   g_w2T[(size_t)ZD2*HID];
__device__              float  g_b1f[HID];
__device__              float  g_b2f[ZD2];
__device__ __align__(16) float g_XW[(size_t)MR*G4];      // 512 MB x-side pre-activations
__device__ __align__(16) f16   g_hseq[(size_t)MR*HID];   // 64 MB
__device__ __align__(16) f16   g_tmp1[(size_t)MR*HID];   // 64 MB
// h broadcast ring: one fresh 64x512 slot per timestep, packed 4 cols / u64.
// Slots 1..T pre-filled with sentinel 0xFFFF... (f16 -NaN, unreachable for
// h = o*tanh(c)); the DATA is the synchronization flag.
__device__ __align__(16) u64   g_hstep[(size_t)(T_SEQ+1)*NB*128];
__device__              int    g_in_fp32;

// ---------------- helpers ----------------
__device__ inline float bf2f(u16 u){ union{u32 i; float f;} v; v.i = ((u32)u)<<16; return v.f; }
__device__ inline u16  f2bf(float f){ union{u32 i; float f;} v; v.f = f; u32 u = v.i;
                                      return (u16)((u + 0x7fffu + ((u>>16)&1u))>>16); }
__device__ inline float load_in(const void* p, size_t i){
  return g_in_fp32 ? ((const float*)p)[i] : bf2f(((const u16*)p)[i]);
}
__device__ inline float fsig(float x){
  return __builtin_amdgcn_rcpf(1.f + __builtin_amdgcn_exp2f(-1.44269504f*x));
}
__device__ inline float ftanh(float x){
  x = fminf(fmaxf(x, -10.f), 10.f);
  float e = __builtin_amdgcn_exp2f(2.88539008f*x);
  return (e - 1.f) * __builtin_amdgcn_rcpf(e + 1.f);
}
__device__ inline int slice_ok(u32x4 v){
  return !(((v.x & v.y) == 0xFFFFFFFFu) | ((v.z & v.w) == 0xFFFFFFFFu));
}

// ---------------- dtype probe ----------------
__global__ void k_probe(const void* x){
  __shared__ int cnt;
  if (threadIdx.x == 0) cnt = 0;
  __syncthreads();
  int loc = 0;
  for (int i = threadIdx.x; i < 4096; i += 256){
    float a = fabsf(bf2f(((const u16*)x)[i]));
    if (a > 0.01f && a < 10.f) loc++;
  }
  atomicAdd(&cnt, loc);
  __syncthreads();
  if (threadIdx.x == 0) g_in_fp32 = (cnt < 3276) ? 1 : 0;
}

// ---------------- init: h slot0 = 0, fp32 biases ----------------
__global__ void k_init(const void* b1, const void* b2){
  int i = blockIdx.x*256 + threadIdx.x;
  if (i < HID)        g_b1f[i] = load_in(b1, i);
  if (i < ZD2)        g_b2f[i] = load_in(b2, i);
  if (i < NB*128)     g_hstep[i] = 0ULL;      // slot 0 = h_0 = zeros
}

// ---------------- sentinel-fill ring slots 1..T ----------------
__global__ void k_fill(){
  size_t i = (size_t)blockIdx.x*256 + threadIdx.x;
  u64* p = g_hstep + (size_t)NB*128;
  const size_t n = (size_t)T_SEQ*NB*128;
  for (size_t j = i; j < n; j += (size_t)4096*256) p[j] = ~0ULL;
}

// ---------------- combine conv_w@Wx -> CWx^T, and bb = conv_b@Wx + b ----------------
__global__ void k_combine(const void* conv_w, const void* conv_b, const void* Wx, const void* b){
  int j  = blockIdx.x*256 + threadIdx.x;  // 0..2047
  int kc = blockIdx.y;                    // 0..384 (384 = bias row)
  float acc = 0.f;
  if (kc < KC){
    for (int m = 0; m < HID; ++m)
      acc += load_in(conv_w, (size_t)kc*HID + m) * load_in(Wx, (size_t)m*G4 + j);
    g_cwxt[(size_t)j*KC + kc] = (f16)acc;
  } else {
    for (int m = 0; m < HID; ++m)
      acc += load_in(conv_b, m) * load_in(Wx, (size_t)m*G4 + j);
    g_bb[j] = acc + load_in(b, j);
  }
}

// ---------------- transposes (src [R][C] -> dst [C][R]) ----------------
__device__ inline void trans_body(const void* src, f16* dst, int R, int C){
  size_t i = (size_t)blockIdx.x*256 + threadIdx.x;
  if (i >= (size_t)R*C) return;
  int c = (int)(i / (size_t)R), r = (int)(i % (size_t)R);
  dst[i] = (f16)load_in(src, (size_t)r*C + c);
}
__global__ void k_trans_wh(const void* Wh){ trans_body(Wh, g_whT, HID, G4); }
__global__ void k_trans_w1(const void* W1){ trans_body(W1, g_w1T, HID, HID); }
__global__ void k_trans_w2(const void* W2){ trans_body(W2, g_w2T, HID, ZD2); }

// ---------------- build sliding-window matrix (SAME pad) ----------------
__global__ void k_xwin(const void* x){
  size_t i = (size_t)blockIdx.x*256 + threadIdx.x;
  if (i >= (size_t)MR*KC) return;
  int row = (int)(i / KC), kc = (int)(i % KC);
  int k = kc >> 7, c = kc & 127;
  int b = row >> 10, t = row & 1023;
  int ts = t - 1 + k;
  float v = 0.f;
  if (ts >= 0 && ts < T_SEQ) v = load_in(x, ((size_t)b*T_SEQ + ts)*128 + c);
  g_xwin[i] = (f16)v;
}

// ---------------- generic MFMA f16 GEMM: C = act(A[M,K] @ BT[N,K]^T + bias) ----------------
template<int MODE, int K>
__device__ inline void gemm_body(const f16* __restrict__ A, const f16* __restrict__ BT,
                                 const float* __restrict__ bias, void* __restrict__ C, int N){
  const int tid = threadIdx.x;
  const int w = tid >> 6, lane = tid & 63;
  const int q = lane >> 4, ln = lane & 15;
  const int n0 = blockIdx.x * 128;
  const int m0 = blockIdx.y * 64;
  const f16* ap = A + (size_t)(m0 + w*16 + ln)*K + q*8;
  const f16* bp = BT + (size_t)(n0 + ln)*K + q*8;
  f32x4 acc[8] = {};
  #pragma unroll 4
  for (int k = 0; k < K; k += 32){
    f16x8 af = *(const f16x8*)(ap + k);
    #pragma unroll
    for (int nt = 0; nt < 8; ++nt){
      f16x8 bf = *(const f16x8*)(bp + (size_t)nt*16*K + k);
      acc[nt] = __builtin_amdgcn_mfma_f32_16x16x32_f16(af, bf, acc[nt], 0, 0, 0);
    }
  }
  const int f32o = g_in_fp32;
  #pragma unroll
  for (int nt = 0; nt < 8; ++nt){
    const int col = n0 + nt*16 + ln;
    const float bv = bias[col];
    #pragma unroll
    for (int r = 0; r < 4; ++r){
      const int row = m0 + w*16 + q*4 + r;
      float v = acc[nt][r] + bv;
      if (MODE == 0){
        ((float*)C)[(size_t)row*N + col] = v;
      } else if (MODE == 1){
        ((f16*)C)[(size_t)row*N + col] = (f16)fmaxf(v, 0.f);
      } else {
        size_t idx = (col < 64) ? ((size_t)row*64 + col)
                                : (4194304UL + (size_t)row*64 + (size_t)(col - 64));
        if (f32o) ((float*)C)[idx] = v;
        else      ((u16*)C)[idx]   = f2bf(v);
      }
    }
  }
}
__global__ __launch_bounds__(256) void k_gemm_xw(){   gemm_body<0,KC >(g_xwin, g_cwxt, g_bb,  g_XW,   G4 ); }
__global__ __launch_bounds__(256) void k_gemm_mlp1(){ gemm_body<1,HID>(g_hseq, g_w1T,  g_b1f, g_tmp1, HID); }
__global__ __launch_bounds__(256) void k_gemm_mlp2(void* out){ gemm_body<2,HID>(g_tmp1, g_w2T, g_b2f, out, ZD2); }

// ---------------- persistent LSTM ----------------
// Arrival-ordered per-slice consumption:
//  - 16 h-loads (16B each) + 8 XW loads bulk-issued in asm, then per-slice
//    counted s_waitcnt vmcnt(23-kk): slices consumed AS THEY ARRIVE, their
//    MFMAs overlap the wait for later slices (vmcnt retires in issue order).
//  - straggler slices pay a targeted 16B reload + vmcnt(0) only.
//  - Wh in LDS (stride 528 f16 = 2-way bank alias = free); no Wh memory
//    traffic in the loop (fixes R1's rematerialization regression).
//  - mid-body vmcnt(0) fence (dataflow-tied to XW outputs) sits BEFORE the
//    publish stores, so store-acks never get drained on the critical path.
__global__ __launch_bounds__(256, 1) void k_lstm(){
  __shared__ __align__(16) f16 whs[32*WPAD];
  const int g   = blockIdx.x;
  const int tid = threadIdx.x;
  const int w = tid >> 6, lane = tid & 63;
  const int q = lane >> 4, ln = lane & 15;
  const int  c8 = ln & 7;
  const bool lo = ln < 8;
  const int  zc0  = (lo ? 0 : HID)       + g*8 + c8;   // i | f column in XW
  const int  zc1  = (lo ? 2*HID : 3*HID) + g*8 + c8;   // g | o column in XW
  const int  colh = g*8 + c8;
  const int  am   = w*16 + ln;                          // A-frag row (batch)

  // ---- Wh slice -> LDS (rows 0-7:i, 8-15:f, 16-23:g, 24-31:o) ----
  for (int idx = tid; idx < 32*HID; idx += 256){
    int r = idx >> 9, k = idx & 511;
    int zcol = (r >> 3)*HID + g*8 + (r & 7);
    whs[r*WPAD + k] = g_whT[(size_t)zcol*HID + k];
  }
  __syncthreads();

  float c_st[4] = {0.f, 0.f, 0.f, 0.f};

  // ---- XW: current values (t=0) + prefetch pointers (t=1) ----
  size_t rowb[4];
  #pragma unroll
  for (int r = 0; r < 4; ++r) rowb[r] = (size_t)(w*16 + q*4 + r)*T_SEQ*G4;
  float xwa[4], xwb[4];
  #pragma unroll
  for (int r = 0; r < 4; ++r){
    xwa[r] = g_XW[rowb[r] + zc0];
    xwb[r] = g_XW[rowb[r] + zc1];
  }
  asm volatile("s_waitcnt vmcnt(0)"
    : "+v"(xwa[0]), "+v"(xwa[1]), "+v"(xwa[2]), "+v"(xwa[3]),
      "+v"(xwb[0]), "+v"(xwb[1]), "+v"(xwb[2]), "+v"(xwb[3]) :: "memory");
  u64 pxa[4], pxb[4];
  #pragma unroll
  for (int r = 0; r < 4; ++r){
    pxa[r] = (u64)(const void*)&g_XW[rowb[r] + (size_t)G4 + zc0];
    pxb[r] = (u64)(const void*)&g_XW[rowb[r] + (size_t)G4 + zc1];
  }

  // per-lane byte address of this lane's h fragment in slot 0
  u64 addr = (u64)(const void*)(g_hstep + ((size_t)am)*128 + (size_t)q*2);

  #pragma unroll 1
  for (int t = 0; t < T_SEQ; ++t){
    u32x4 hr[16];
    // ---- bulk-issue 16 h-slice loads (NO wait) ----
    asm volatile(
      "global_load_dwordx4 %0, %16, off sc0 sc1\n"
      "global_load_dwordx4 %1, %16, off offset:64 sc0 sc1\n"
      "global_load_dwordx4 %2, %16, off offset:128 sc0 sc1\n"
      "global_load_dwordx4 %3, %16, off offset:192 sc0 sc1\n"
      "global_load_dwordx4 %4, %16, off offset:256 sc0 sc1\n"
      "global_load_dwordx4 %5, %16, off offset:320 sc0 sc1\n"
      "global_load_dwordx4 %6, %16, off offset:384 sc0 sc1\n"
      "global_load_dwordx4 %7, %16, off offset:448 sc0 sc1\n"
      "global_load_dwordx4 %8, %16, off offset:512 sc0 sc1\n"
      "global_load_dwordx4 %9, %16, off offset:576 sc0 sc1\n"
      "global_load_dwordx4 %10, %16, off offset:640 sc0 sc1\n"
      "global_load_dwordx4 %11, %16, off offset:704 sc0 sc1\n"
      "global_load_dwordx4 %12, %16, off offset:768 sc0 sc1\n"
      "global_load_dwordx4 %13, %16, off offset:832 sc0 sc1\n"
      "global_load_dwordx4 %14, %16, off offset:896 sc0 sc1\n"
      "global_load_dwordx4 %15, %16, off offset:960 sc0 sc1"
      : "=&v"(hr[0]),  "=&v"(hr[1]),  "=&v"(hr[2]),  "=&v"(hr[3]),
        "=&v"(hr[4]),  "=&v"(hr[5]),  "=&v"(hr[6]),  "=&v"(hr[7]),
        "=&v"(hr[8]),  "=&v"(hr[9]),  "=&v"(hr[10]), "=&v"(hr[11]),
        "=&v"(hr[12]), "=&v"(hr[13]), "=&v"(hr[14]), "=&v"(hr[15])
      : "v"(addr)
      : "memory");
    // ---- issue 8 XW loads for t+1 (younger than all h-loads) ----
    float xn0,xn1,xn2,xn3,xn4,xn5,xn6,xn7;
    asm volatile(
      "global_load_dword %0, %8, off\n"
      "global_load_dword %1, %9, off\n"
      "global_load_dword %2, %10, off\n"
      "global_load_dword %3, %11, off\n"
      "global_load_dword %4, %12, off\n"
      "global_load_dword %5, %13, off\n"
      "global_load_dword %6, %14, off\n"
      "global_load_dword %7, %15, off"
      : "=&v"(xn0), "=&v"(xn1), "=&v"(xn2), "=&v"(xn3),
        "=&v"(xn4), "=&v"(xn5), "=&v"(xn6), "=&v"(xn7)
      : "v"(pxa[0]), "v"(pxa[1]), "v"(pxa[2]), "v"(pxa[3]),
        "v"(pxb[0]), "v"(pxb[1]), "v"(pxb[2]), "v"(pxb[3])
      : "memory");

    f32x4 a0a = {0.f,0.f,0.f,0.f}, a0b = {0.f,0.f,0.f,0.f};
    f32x4 a1a = {0.f,0.f,0.f,0.f}, a1b = {0.f,0.f,0.f,0.f};

    // per-slice: counted wait (dataflow-tied), targeted retry, 2 MFMAs
#define H_SLICE(KK, NSTR, OFFSTR)                                              \
    {                                                                          \
      asm volatile("s_waitcnt vmcnt(" NSTR ")"                                 \
                   : "+v"(hr[KK]) :: "memory");                                \
      while (!__all(slice_ok(hr[KK]))){                                        \
        asm volatile("global_load_dwordx4 %0, %1, off offset:" OFFSTR          \
                     " sc0 sc1\n\ts_waitcnt vmcnt(0)"                          \
                     : "=&v"(hr[KK]) : "v"(addr) : "memory");                  \
      }                                                                        \
      f16x8 af = __builtin_bit_cast(f16x8, hr[KK]);                            \
      f16x8 b0 = *(const f16x8*)&whs[(     ln)*WPAD + (KK)*32 + q*8];          \
      f16x8 b1 = *(const f16x8*)&whs[(16 + ln)*WPAD + (KK)*32 + q*8];          \
      if ((KK) & 1){                                                           \
        a0b = __builtin_amdgcn_mfma_f32_16x16x32_f16(af, b0, a0b, 0, 0, 0);    \
        a1b = __builtin_amdgcn_mfma_f32_16x16x32_f16(af, b1, a1b, 0, 0, 0);    \
      } else {                                                                 \
        a0a = __builtin_amdgcn_mfma_f32_16x16x32_f16(af, b0, a0a, 0, 0, 0);    \
        a1a = __builtin_amdgcn_mfma_f32_16x16x32_f16(af, b1, a1a, 0, 0, 0);    \
      }                                                                        \
    }
    H_SLICE(0,  "23", "0")
    H_SLICE(1,  "22", "64")
    H_SLICE(2,  "21", "128")
    H_SLICE(3,  "20", "192")
    H_SLICE(4,  "19", "256")
    H_SLICE(5,  "18", "320")
    H_SLICE(6,  "17", "384")
    H_SLICE(7,  "16", "448")
    H_SLICE(8,  "15", "512")
    H_SLICE(9,  "14", "576")
    H_SLICE(10, "13", "640")
    H_SLICE(11, "12", "704")
    H_SLICE(12, "11", "768")
    H_SLICE(13, "10", "832")
    H_SLICE(14, "9",  "896")
    H_SLICE(15, "8",  "960")
#undef H_SLICE

    // ---- XW fence BEFORE any store is issued (no store-ack on the chain) ----
    asm volatile("s_waitcnt vmcnt(0)"
      : "+v"(xn0), "+v"(xn1), "+v"(xn2), "+v"(xn3),
        "+v"(xn4), "+v"(xn5), "+v"(xn6), "+v"(xn7) :: "memory");

    f32x4 a0 = a0a + a0b;
    f32x4 a1 = a1a + a1b;

    // ---- gates + fire-and-forget h publish ----
    f16 h16v[4];
    #pragma unroll
    for (int r = 0; r < 4; ++r){
      float z0 = a0[r] + xwa[r];          // i (lo) | f (hi)
      float z1 = a1[r] + xwb[r];          // g (lo) | o (hi)
      float zf = __shfl_xor(z0, 8, 64);
      float zo = __shfl_xor(z1, 8, 64);
      float iv = fsig(z0);
      float fv = fsig(zf);
      float gv = ftanh(z1);
      float ov = fsig(zo);
      float cn = fv*c_st[r] + iv*gv;
      c_st[r] = cn;
      float hvf = ov*ftanh(cn);
      f16 h16 = (f16)hvf;
      h16v[r] = h16;
      u32 me = (u32)__builtin_bit_cast(u16, h16);
      u32 p1 = me | (((u32)__shfl_xor((int)me, 1, 64)) << 16);   // cols c8,c8+1 (even c8)
      u32 p2 = (u32)__shfl_xor((int)p1, 2, 64);                  // cols c8+2,c8+3
      u64 pk = (u64)p1 | ((u64)p2 << 32);
      if (lo && (c8 & 3) == 0){
        int m = w*16 + q*4 + r;
        __hip_atomic_store(g_hstep + ((size_t)(t+1)*NB + m)*128 + (size_t)g*2 + (c8>>2),
                           pk, __ATOMIC_RELAXED, __HIP_MEMORY_SCOPE_AGENT);
      }
    }
    // hseq stores: consumed only by k_gemm_mlp1 (cross-kernel flush at dispatch end)
    if (lo){
      #pragma unroll
      for (int r = 0; r < 4; ++r){
        int m = w*16 + q*4 + r;
        g_hseq[((size_t)m*T_SEQ + t)*HID + colh] = h16v[r];
      }
    }
    // rotate XW double-buffer, advance pointers
    xwa[0]=xn0; xwa[1]=xn1; xwa[2]=xn2; xwa[3]=xn3;
    xwb[0]=xn4; xwb[1]=xn5; xwb[2]=xn6; xwb[3]=xn7;
    if (t < T_SEQ-2){
      #pragma unroll
      for (int r = 0; r < 4; ++r){ pxa[r] += (u64)G4*4; pxb[r] += (u64)G4*4; }
    }
    addr += (u64)NB*128*8;   // next ring slot
  }
}

// ---------------- launch ----------------
extern "C" void kernel_launch(void* const* d_in, const int* in_sizes, int n_in,
                              void* d_out, int out_size, void* d_ws, size_t ws_size,
                              hipStream_t stream){
  const void* x      = d_in[0];
  const void* conv_w = d_in[1];
  const void* conv_b = d_in[2];
  const void* Wx     = d_in[3];
  const void* Wh     = d_in[4];
  const void* b      = d_in[5];
  const void* W1     = d_in[6];
  const void* b1     = d_in[7];
  const void* W2     = d_in[8];
  const void* b2     = d_in[9];
  (void)in_sizes; (void)n_in; (void)out_size; (void)d_ws; (void)ws_size;

  hipLaunchKernelGGL(k_probe,   dim3(1),        dim3(256), 0, stream, x);
  hipLaunchKernelGGL(k_init,    dim3(256),      dim3(256), 0, stream, b1, b2);
  hipLaunchKernelGGL(k_fill,    dim3(4096),     dim3(256), 0, stream);
  hipLaunchKernelGGL(k_combine, dim3(8, 385),   dim3(256), 0, stream, conv_w, conv_b, Wx, b);
  hipLaunchKernelGGL(k_trans_wh,dim3(4096),     dim3(256), 0, stream, Wh);
  hipLaunchKernelGGL(k_trans_w1,dim3(1024),     dim3(256), 0, stream, W1);
  hipLaunchKernelGGL(k_trans_w2,dim3(256),      dim3(256), 0, stream, W2);
  hipLaunchKernelGGL(k_xwin,    dim3(98304),    dim3(256), 0, stream, x);
  hipLaunchKernelGGL(k_gemm_xw, dim3(16, 1024), dim3(256), 0, stream);
  hipLaunchKernelGGL(k_lstm,    dim3(64),       dim3(256), 0, stream);
  hipLaunchKernelGGL(k_gemm_mlp1, dim3(4, 1024), dim3(256), 0, stream);
  hipLaunchKernelGGL(k_gemm_mlp2, dim3(1, 1024), dim3(256), 0, stream, d_out);
}

// Round 3
// 9012.759 us; speedup vs baseline: 1.5093x; 1.5093x over previous
//
#include <hip/hip_runtime.h>
#include <math.h>

typedef unsigned short u16;
typedef unsigned int   u32;
typedef unsigned long long u64;
typedef _Float16 f16;
typedef __attribute__((ext_vector_type(8))) _Float16 f16x8;
typedef __attribute__((ext_vector_type(4))) float    f32x4;
typedef __attribute__((ext_vector_type(4))) u32      u32x4;

#define T_SEQ 1024
#define NB    64
#define HID   512
#define KC    384       // 3*128 combined conv+Wx K
#define G4    2048      // 4*HID
#define MR    (NB*T_SEQ) // 65536
#define ZD2   128       // 2*ZD
#define NWG   32        // LSTM workgroups (each owns 16 hidden cols)

// ---------------- static device buffers ----------------
__device__ __align__(16) f16   g_xwin[(size_t)MR*KC];    // 48 MB window-matrix (f16)
__device__ __align__(16) f16   g_cwxt[(size_t)G4*KC];    // combined (conv_w@Wx)^T  [n][k]
__device__              float  g_bb[G4];                 // conv_b@Wx + b
__device__ __align__(16) f16   g_whT[(size_t)G4*HID];    // Wh^T [2048][512]
__device__ __align__(16) f16   g_w1T[(size_t)HID*HID];
__device__ __align__(16) f16   g_w2T[(size_t)ZD2*HID];
__device__              float  g_b1f[HID];
__device__              float  g_b2f[ZD2];
__device__ __align__(16) float g_XW[(size_t)MR*G4];      // 512 MB x-side pre-activations
__device__ __align__(16) f16   g_hseq[(size_t)MR*HID];   // 64 MB
__device__ __align__(16) f16   g_tmp1[(size_t)MR*HID];   // 64 MB
// h broadcast ring: one fresh 64x512 f16 slot (64KB) per timestep.
// Slots 1..T pre-filled with sentinel 0xFFFF (f16 -NaN, unreachable for
// h = o*tanh(c)); the DATA is the synchronization flag (per-u32 granules).
__device__ __align__(16) u64   g_hstep[(size_t)(T_SEQ+1)*NB*128];
__device__              int    g_in_fp32;

// ---------------- helpers ----------------
__device__ inline float bf2f(u16 u){ union{u32 i; float f;} v; v.i = ((u32)u)<<16; return v.f; }
__device__ inline u16  f2bf(float f){ union{u32 i; float f;} v; v.f = f; u32 u = v.i;
                                      return (u16)((u + 0x7fffu + ((u>>16)&1u))>>16); }
__device__ inline float load_in(const void* p, size_t i){
  return g_in_fp32 ? ((const float*)p)[i] : bf2f(((const u16*)p)[i]);
}
__device__ inline float fsig(float x){
  return __builtin_amdgcn_rcpf(1.f + __builtin_amdgcn_exp2f(-1.44269504f*x));
}
__device__ inline float ftanh(float x){
  x = fminf(fmaxf(x, -10.f), 10.f);
  float e = __builtin_amdgcn_exp2f(2.88539008f*x);
  return (e - 1.f) * __builtin_amdgcn_rcpf(e + 1.f);
}
// valid iff NO u32 granule is the sentinel (each u32 written by one store)
__device__ inline int slice_ok(u32x4 v){
  return (v.x != 0xFFFFFFFFu) & (v.y != 0xFFFFFFFFu) &
         (v.z != 0xFFFFFFFFu) & (v.w != 0xFFFFFFFFu);
}

// ---------------- dtype probe ----------------
__global__ void k_probe(const void* x){
  __shared__ int cnt;
  if (threadIdx.x == 0) cnt = 0;
  __syncthreads();
  int loc = 0;
  for (int i = threadIdx.x; i < 4096; i += 256){
    float a = fabsf(bf2f(((const u16*)x)[i]));
    if (a > 0.01f && a < 10.f) loc++;
  }
  atomicAdd(&cnt, loc);
  __syncthreads();
  if (threadIdx.x == 0) g_in_fp32 = (cnt < 3276) ? 1 : 0;
}

// ---------------- init: h slot0 = 0, fp32 biases ----------------
__global__ void k_init(const void* b1, const void* b2){
  int i = blockIdx.x*256 + threadIdx.x;
  if (i < HID)        g_b1f[i] = load_in(b1, i);
  if (i < ZD2)        g_b2f[i] = load_in(b2, i);
  if (i < NB*128)     g_hstep[i] = 0ULL;      // slot 0 = h_0 = zeros
}

// ---------------- sentinel-fill ring slots 1..T ----------------
__global__ void k_fill(){
  size_t i = (size_t)blockIdx.x*256 + threadIdx.x;
  u64* p = g_hstep + (size_t)NB*128;
  const size_t n = (size_t)T_SEQ*NB*128;
  for (size_t j = i; j < n; j += (size_t)4096*256) p[j] = ~0ULL;
}

// ---------------- combine conv_w@Wx -> CWx^T, and bb = conv_b@Wx + b ----------------
__global__ void k_combine(const void* conv_w, const void* conv_b, const void* Wx, const void* b){
  int j  = blockIdx.x*256 + threadIdx.x;  // 0..2047
  int kc = blockIdx.y;                    // 0..384 (384 = bias row)
  float acc = 0.f;
  if (kc < KC){
    for (int m = 0; m < HID; ++m)
      acc += load_in(conv_w, (size_t)kc*HID + m) * load_in(Wx, (size_t)m*G4 + j);
    g_cwxt[(size_t)j*KC + kc] = (f16)acc;
  } else {
    for (int m = 0; m < HID; ++m)
      acc += load_in(conv_b, m) * load_in(Wx, (size_t)m*G4 + j);
    g_bb[j] = acc + load_in(b, j);
  }
}

// ---------------- transposes (src [R][C] -> dst [C][R]) ----------------
__device__ inline void trans_body(const void* src, f16* dst, int R, int C){
  size_t i = (size_t)blockIdx.x*256 + threadIdx.x;
  if (i >= (size_t)R*C) return;
  int c = (int)(i / (size_t)R), r = (int)(i % (size_t)R);
  dst[i] = (f16)load_in(src, (size_t)r*C + c);
}
__global__ void k_trans_wh(const void* Wh){ trans_body(Wh, g_whT, HID, G4); }
__global__ void k_trans_w1(const void* W1){ trans_body(W1, g_w1T, HID, HID); }
__global__ void k_trans_w2(const void* W2){ trans_body(W2, g_w2T, HID, ZD2); }

// ---------------- build sliding-window matrix (SAME pad) ----------------
__global__ void k_xwin(const void* x){
  size_t i = (size_t)blockIdx.x*256 + threadIdx.x;
  if (i >= (size_t)MR*KC) return;
  int row = (int)(i / KC), kc = (int)(i % KC);
  int k = kc >> 7, c = kc & 127;
  int b = row >> 10, t = row & 1023;
  int ts = t - 1 + k;
  float v = 0.f;
  if (ts >= 0 && ts < T_SEQ) v = load_in(x, ((size_t)b*T_SEQ + ts)*128 + c);
  g_xwin[i] = (f16)v;
}

// ---------------- generic MFMA f16 GEMM: C = act(A[M,K] @ BT[N,K]^T + bias) ----------------
template<int MODE, int K>
__device__ inline void gemm_body(const f16* __restrict__ A, const f16* __restrict__ BT,
                                 const float* __restrict__ bias, void* __restrict__ C, int N){
  const int tid = threadIdx.x;
  const int w = tid >> 6, lane = tid & 63;
  const int q = lane >> 4, ln = lane & 15;
  const int n0 = blockIdx.x * 128;
  const int m0 = blockIdx.y * 64;
  const f16* ap = A + (size_t)(m0 + w*16 + ln)*K + q*8;
  const f16* bp = BT + (size_t)(n0 + ln)*K + q*8;
  f32x4 acc[8] = {};
  #pragma unroll 4
  for (int k = 0; k < K; k += 32){
    f16x8 af = *(const f16x8*)(ap + k);
    #pragma unroll
    for (int nt = 0; nt < 8; ++nt){
      f16x8 bf = *(const f16x8*)(bp + (size_t)nt*16*K + k);
      acc[nt] = __builtin_amdgcn_mfma_f32_16x16x32_f16(af, bf, acc[nt], 0, 0, 0);
    }
  }
  const int f32o = g_in_fp32;
  #pragma unroll
  for (int nt = 0; nt < 8; ++nt){
    const int col = n0 + nt*16 + ln;
    const float bv = bias[col];
    #pragma unroll
    for (int r = 0; r < 4; ++r){
      const int row = m0 + w*16 + q*4 + r;
      float v = acc[nt][r] + bv;
      if (MODE == 0){
        ((float*)C)[(size_t)row*N + col] = v;
      } else if (MODE == 1){
        ((f16*)C)[(size_t)row*N + col] = (f16)fmaxf(v, 0.f);
      } else {
        size_t idx = (col < 64) ? ((size_t)row*64 + col)
                                : (4194304UL + (size_t)row*64 + (size_t)(col - 64));
        if (f32o) ((float*)C)[idx] = v;
        else      ((u16*)C)[idx]   = f2bf(v);
      }
    }
  }
}
__global__ __launch_bounds__(256) void k_gemm_xw(){   gemm_body<0,KC >(g_xwin, g_cwxt, g_bb,  g_XW,   G4 ); }
__global__ __launch_bounds__(256) void k_gemm_mlp1(){ gemm_body<1,HID>(g_hseq, g_w1T,  g_b1f, g_tmp1, HID); }
__global__ __launch_bounds__(256) void k_gemm_mlp2(void* out){ gemm_body<2,HID>(g_tmp1, g_w2T, g_b2f, out, ZD2); }

// ---------------- persistent LSTM ----------------
// 32 WGs, each owns 16 hidden cols (64 gate-cols). Gate-colocated tiling:
// N-tile nt = gate, so one thread holds i,f,g,o for the SAME hidden col in
// acc[0..3] -- zero shuffles for the cell math. Sentinel dataflow protocol
// (no flags, no barriers, nothing fencing the publish path); selective
// re-poll re-issues only invalid 16B slices, one vmcnt(0) per round.
// Wh slice in LDS (exactly 64KB) with XOR swizzle k^=(row&7)<<3 to kill the
// 16-way bank conflict of the 1KB row stride.
__global__ __launch_bounds__(256, 1) void k_lstm(){
  __shared__ __align__(16) f16 whs[64*512];   // 64 KB
  const int g   = blockIdx.x;                 // 0..31
  const int tid = threadIdx.x;
  const int w = tid >> 6, lane = tid & 63;
  const int q = lane >> 4, ln = lane & 15;
  const int jcol = g*16 + ln;                 // this thread's hidden col
  const int am   = w*16 + ln;                 // A-frag row (batch)

  // ---- stage Wh slice -> LDS, vectorized 16B, swizzled ----
  // local row n = nt*16 + l  (nt = gate), global z-col = nt*512 + g*16 + l
  for (int idx = tid; idx < 64*64; idx += 256){
    int n = idx >> 6, k8 = (idx & 63) * 8;
    int zcol = (n >> 4)*HID + g*16 + (n & 15);
    *(f16x8*)&whs[(n << 9) | (k8 ^ ((n & 7) << 3))] =
        *(const f16x8*)&g_whT[(size_t)zcol*HID + k8];
  }
  __syncthreads();

  float c_st[4] = {0.f, 0.f, 0.f, 0.f};

  // ---- XW addressing: col = nt*512 + jcol, row = w*16+q*4+r ----
  size_t rowb[4];
  #pragma unroll
  for (int r = 0; r < 4; ++r) rowb[r] = (size_t)(w*16 + q*4 + r)*T_SEQ*G4;
  float xw[4][4];   // [nt][r], fully unrolled accesses only
  #pragma unroll
  for (int nt = 0; nt < 4; ++nt)
    #pragma unroll
    for (int r = 0; r < 4; ++r)
      xw[nt][r] = g_XW[rowb[r] + nt*HID + jcol];

  // per-lane byte address of this lane's h fragment in slot 0
  u64 addr = (u64)(const void*)(g_hstep + ((size_t)am)*128 + (size_t)q*2);

  #pragma unroll 1
  for (int t = 0; t < T_SEQ; ++t){
    u32x4 hr[16];
    // ---- issue all 16 h-slice loads (no wait) ----
#define ISSUE(KK, OFF)                                                         \
    asm volatile("global_load_dwordx4 %0, %1, off offset:" OFF " sc0 sc1"      \
                 : "=v"(hr[KK]) : "v"(addr) : "memory");
    ISSUE(0,"0")   ISSUE(1,"64")   ISSUE(2,"128")  ISSUE(3,"192")
    ISSUE(4,"256") ISSUE(5,"320")  ISSUE(6,"384")  ISSUE(7,"448")
    ISSUE(8,"512") ISSUE(9,"576")  ISSUE(10,"640") ISSUE(11,"704")
    ISSUE(12,"768")ISSUE(13,"832") ISSUE(14,"896") ISSUE(15,"960")

    // ---- prefetch XW for t+1 (plain loads; drained by first poll round) ----
    const int tn = (t+1 < T_SEQ) ? (t+1) : t;
    float xn[4][4];
    #pragma unroll
    for (int nt = 0; nt < 4; ++nt)
      #pragma unroll
      for (int r = 0; r < 4; ++r)
        xn[nt][r] = g_XW[rowb[r] + (size_t)tn*G4 + nt*HID + jcol];

    // ---- poll: one vmcnt(0) per round, re-issue ONLY invalid slices ----
    u32 need = 0xFFFFu;
    for (;;){
      asm volatile("s_waitcnt vmcnt(0)"
        : "+v"(hr[0]),  "+v"(hr[1]),  "+v"(hr[2]),  "+v"(hr[3]),
          "+v"(hr[4]),  "+v"(hr[5]),  "+v"(hr[6]),  "+v"(hr[7]),
          "+v"(hr[8]),  "+v"(hr[9]),  "+v"(hr[10]), "+v"(hr[11]),
          "+v"(hr[12]), "+v"(hr[13]), "+v"(hr[14]), "+v"(hr[15])
        :: "memory");
      u32 nb = 0;
      #pragma unroll
      for (int kk = 0; kk < 16; ++kk)
        if (need & (1u<<kk))
          if (!__all(slice_ok(hr[kk]))) nb |= (1u<<kk);
      if (!nb) break;
      need = nb;
#define REISSUE(KK, OFF)                                                       \
      if (need & (1u<<KK))                                                     \
        asm volatile("global_load_dwordx4 %0, %1, off offset:" OFF " sc0 sc1"  \
                     : "=v"(hr[KK]) : "v"(addr) : "memory");
      REISSUE(0,"0")   REISSUE(1,"64")   REISSUE(2,"128")  REISSUE(3,"192")
      REISSUE(4,"256") REISSUE(5,"320")  REISSUE(6,"384")  REISSUE(7,"448")
      REISSUE(8,"512") REISSUE(9,"576")  REISSUE(10,"640") REISSUE(11,"704")
      REISSUE(12,"768")REISSUE(13,"832") REISSUE(14,"896") REISSUE(15,"960")
#undef REISSUE
    }
#undef ISSUE

    // ---- MFMA: 4 gate-chains x even/odd split (8 independent chains) ----
    f32x4 aA[4] = {}, aB[4] = {};
    #pragma unroll
    for (int kk = 0; kk < 16; ++kk){
      f16x8 af = __builtin_bit_cast(f16x8, hr[kk]);
      #pragma unroll
      for (int nt = 0; nt < 4; ++nt){
        f16x8 bf = *(const f16x8*)&whs[((nt*16 + ln) << 9) |
                                       ((kk*32 + q*8) ^ ((ln & 7) << 3))];
        if (kk & 1) aB[nt] = __builtin_amdgcn_mfma_f32_16x16x32_f16(af, bf, aB[nt], 0, 0, 0);
        else        aA[nt] = __builtin_amdgcn_mfma_f32_16x16x32_f16(af, bf, aA[nt], 0, 0, 0);
      }
    }

    // ---- gates (all lane-local!) + immediate fire-and-forget publish ----
    f16 h16v[4];
    #pragma unroll
    for (int r = 0; r < 4; ++r){
      float zi = aA[0][r] + aB[0][r] + xw[0][r];
      float zf = aA[1][r] + aB[1][r] + xw[1][r];
      float zg = aA[2][r] + aB[2][r] + xw[2][r];
      float zo = aA[3][r] + aB[3][r] + xw[3][r];
      float iv = fsig(zi);
      float fv = fsig(zf);
      float gv = ftanh(zg);
      float ov = fsig(zo);
      float cn = fv*c_st[r] + iv*gv;
      c_st[r] = cn;
      float hvf = ov*ftanh(cn);
      f16 h16 = (f16)hvf;
      h16v[r] = h16;
      u32 me = (u32)__builtin_bit_cast(u16, h16);
      u32 p  = me | (((u32)__shfl_xor((int)me, 1, 64)) << 16);  // cols jcol,jcol+1
      if ((ln & 1) == 0){
        int m = w*16 + q*4 + r;
        __hip_atomic_store((u32*)g_hstep + ((size_t)(t+1)*NB + m)*256 + (jcol >> 1),
                           p, __ATOMIC_RELAXED, __HIP_MEMORY_SCOPE_AGENT);
      }
    }
    // hseq stores: consumed only by k_gemm_mlp1 (flushed at dispatch end)
    #pragma unroll
    for (int r = 0; r < 4; ++r){
      int m = w*16 + q*4 + r;
      g_hseq[((size_t)m*T_SEQ + t)*HID + jcol] = h16v[r];
    }
    // rotate XW buffer
    #pragma unroll
    for (int nt = 0; nt < 4; ++nt)
      #pragma unroll
      for (int r = 0; r < 4; ++r)
        xw[nt][r] = xn[nt][r];
    addr += (u64)NB*128*8;   // next ring slot (64KB)
  }
}

// ---------------- launch ----------------
extern "C" void kernel_launch(void* const* d_in, const int* in_sizes, int n_in,
                              void* d_out, int out_size, void* d_ws, size_t ws_size,
                              hipStream_t stream){
  const void* x      = d_in[0];
  const void* conv_w = d_in[1];
  const void* conv_b = d_in[2];
  const void* Wx     = d_in[3];
  const void* Wh     = d_in[4];
  const void* b      = d_in[5];
  const void* W1     = d_in[6];
  const void* b1     = d_in[7];
  const void* W2     = d_in[8];
  const void* b2     = d_in[9];
  (void)in_sizes; (void)n_in; (void)out_size; (void)d_ws; (void)ws_size;

  hipLaunchKernelGGL(k_probe,   dim3(1),        dim3(256), 0, stream, x);
  hipLaunchKernelGGL(k_init,    dim3(256),      dim3(256), 0, stream, b1, b2);
  hipLaunchKernelGGL(k_fill,    dim3(4096),     dim3(256), 0, stream);
  hipLaunchKernelGGL(k_combine, dim3(8, 385),   dim3(256), 0, stream, conv_w, conv_b, Wx, b);
  hipLaunchKernelGGL(k_trans_wh,dim3(4096),     dim3(256), 0, stream, Wh);
  hipLaunchKernelGGL(k_trans_w1,dim3(1024),     dim3(256), 0, stream, W1);
  hipLaunchKernelGGL(k_trans_w2,dim3(256),      dim3(256), 0, stream, W2);
  hipLaunchKernelGGL(k_xwin,    dim3(98304),    dim3(256), 0, stream, x);
  hipLaunchKernelGGL(k_gemm_xw, dim3(16, 1024), dim3(256), 0, stream);
  hipLaunchKernelGGL(k_lstm,    dim3(NWG),      dim3(256), 0, stream);
  hipLaunchKernelGGL(k_gemm_mlp1, dim3(4, 1024), dim3(256), 0, stream);
  hipLaunchKernelGGL(k_gemm_mlp2, dim3(1, 1024), dim3(256), 0, stream, d_out);
}

// Round 4
// 8119.767 us; speedup vs baseline: 1.6753x; 1.1100x over previous
//
#include <hip/hip_runtime.h>
#include <math.h>

typedef unsigned short u16;
typedef unsigned int   u32;
typedef unsigned long long u64;
typedef _Float16 f16;
typedef __attribute__((ext_vector_type(8))) _Float16 f16x8;
typedef __attribute__((ext_vector_type(4))) float    f32x4;
typedef __attribute__((ext_vector_type(4))) u32      u32x4;

#define T_SEQ 1024
#define NB    64
#define HID   512
#define KC    384       // 3*128 combined conv+Wx K
#define G4    2048      // 4*HID
#define MR    (NB*T_SEQ) // 65536
#define ZD2   128       // 2*ZD
#define NWG   32        // LSTM workgroups (each owns 16 hidden cols)
#define NHEAT 192       // heater workgroups (DPM clock experiment)

// ---------------- static device buffers ----------------
__device__ __align__(16) f16   g_xwin[(size_t)MR*KC];    // 48 MB window-matrix (f16)
__device__ __align__(16) f16   g_cwxt[(size_t)G4*KC];    // combined (conv_w@Wx)^T  [n][k]
__device__              float  g_bb[G4];                 // conv_b@Wx + b
__device__ __align__(16) f16   g_whT[(size_t)G4*HID];    // Wh^T [2048][512]
__device__ __align__(16) f16   g_w1T[(size_t)HID*HID];
__device__ __align__(16) f16   g_w2T[(size_t)ZD2*HID];
__device__              float  g_b1f[HID];
__device__              float  g_b2f[ZD2];
__device__ __align__(16) float g_XW[(size_t)MR*G4];      // 512 MB x-side pre-activations
__device__ __align__(16) f16   g_hseq[(size_t)MR*HID];   // 64 MB
__device__ __align__(16) f16   g_tmp1[(size_t)MR*HID];   // 64 MB
// h broadcast ring: one fresh 64x512 f16 slot (64KB) per timestep.
// Slots 1..T pre-filled with sentinel 0xFFFF (f16 -NaN, unreachable for
// h = o*tanh(c)); the DATA is the synchronization flag (per-u32 granules).
__device__ __align__(16) u64   g_hstep[(size_t)(T_SEQ+1)*NB*128];
__device__              int    g_in_fp32;
__device__              int    g_done;

// ---------------- helpers ----------------
__device__ inline float bf2f(u16 u){ union{u32 i; float f;} v; v.i = ((u32)u)<<16; return v.f; }
__device__ inline u16  f2bf(float f){ union{u32 i; float f;} v; v.f = f; u32 u = v.i;
                                      return (u16)((u + 0x7fffu + ((u>>16)&1u))>>16); }
__device__ inline float load_in(const void* p, size_t i){
  return g_in_fp32 ? ((const float*)p)[i] : bf2f(((const u16*)p)[i]);
}
__device__ inline float fsig(float x){
  return __builtin_amdgcn_rcpf(1.f + __builtin_amdgcn_exp2f(-1.44269504f*x));
}
__device__ inline float ftanh(float x){
  x = fminf(fmaxf(x, -10.f), 10.f);
  float e = __builtin_amdgcn_exp2f(2.88539008f*x);
  return (e - 1.f) * __builtin_amdgcn_rcpf(e + 1.f);
}
// valid iff NO u32 granule is the sentinel (each u32 written by one store)
__device__ inline int slice_ok(u32x4 v){
  return (v.x != 0xFFFFFFFFu) & (v.y != 0xFFFFFFFFu) &
         (v.z != 0xFFFFFFFFu) & (v.w != 0xFFFFFFFFu);
}

// ---------------- dtype probe ----------------
__global__ void k_probe(const void* x){
  __shared__ int cnt;
  if (threadIdx.x == 0) cnt = 0;
  __syncthreads();
  int loc = 0;
  for (int i = threadIdx.x; i < 4096; i += 256){
    float a = fabsf(bf2f(((const u16*)x)[i]));
    if (a > 0.01f && a < 10.f) loc++;
  }
  atomicAdd(&cnt, loc);
  __syncthreads();
  if (threadIdx.x == 0) g_in_fp32 = (cnt < 3276) ? 1 : 0;
}

// ---------------- init: h slot0 = 0, fp32 biases, done flag ----------------
__global__ void k_init(const void* b1, const void* b2){
  int i = blockIdx.x*256 + threadIdx.x;
  if (i == 0)         g_done = 0;
  if (i < HID)        g_b1f[i] = load_in(b1, i);
  if (i < ZD2)        g_b2f[i] = load_in(b2, i);
  if (i < NB*128)     g_hstep[i] = 0ULL;      // slot 0 = h_0 = zeros
}

// ---------------- sentinel-fill ring slots 1..T ----------------
__global__ void k_fill(){
  size_t i = (size_t)blockIdx.x*256 + threadIdx.x;
  u64* p = g_hstep + (size_t)NB*128;
  const size_t n = (size_t)T_SEQ*NB*128;
  for (size_t j = i; j < n; j += (size_t)4096*256) p[j] = ~0ULL;
}

// ---------------- combine conv_w@Wx -> CWx^T, and bb = conv_b@Wx + b ----------------
__global__ void k_combine(const void* conv_w, const void* conv_b, const void* Wx, const void* b){
  int j  = blockIdx.x*256 + threadIdx.x;  // 0..2047
  int kc = blockIdx.y;                    // 0..384 (384 = bias row)
  float acc = 0.f;
  if (kc < KC){
    for (int m = 0; m < HID; ++m)
      acc += load_in(conv_w, (size_t)kc*HID + m) * load_in(Wx, (size_t)m*G4 + j);
    g_cwxt[(size_t)j*KC + kc] = (f16)acc;
  } else {
    for (int m = 0; m < HID; ++m)
      acc += load_in(conv_b, m) * load_in(Wx, (size_t)m*G4 + j);
    g_bb[j] = acc + load_in(b, j);
  }
}

// ---------------- transposes (src [R][C] -> dst [C][R]) ----------------
__device__ inline void trans_body(const void* src, f16* dst, int R, int C){
  size_t i = (size_t)blockIdx.x*256 + threadIdx.x;
  if (i >= (size_t)R*C) return;
  int c = (int)(i / (size_t)R), r = (int)(i % (size_t)R);
  dst[i] = (f16)load_in(src, (size_t)r*C + c);
}
__global__ void k_trans_wh(const void* Wh){ trans_body(Wh, g_whT, HID, G4); }
__global__ void k_trans_w1(const void* W1){ trans_body(W1, g_w1T, HID, HID); }
__global__ void k_trans_w2(const void* W2){ trans_body(W2, g_w2T, HID, ZD2); }

// ---------------- build sliding-window matrix (SAME pad) ----------------
__global__ void k_xwin(const void* x){
  size_t i = (size_t)blockIdx.x*256 + threadIdx.x;
  if (i >= (size_t)MR*KC) return;
  int row = (int)(i / KC), kc = (int)(i % KC);
  int k = kc >> 7, c = kc & 127;
  int b = row >> 10, t = row & 1023;
  int ts = t - 1 + k;
  float v = 0.f;
  if (ts >= 0 && ts < T_SEQ) v = load_in(x, ((size_t)b*T_SEQ + ts)*128 + c);
  g_xwin[i] = (f16)v;
}

// ---------------- generic MFMA f16 GEMM: C = act(A[M,K] @ BT[N,K]^T + bias) ----------------
template<int MODE, int K>
__device__ inline void gemm_body(const f16* __restrict__ A, const f16* __restrict__ BT,
                                 const float* __restrict__ bias, void* __restrict__ C, int N){
  const int tid = threadIdx.x;
  const int w = tid >> 6, lane = tid & 63;
  const int q = lane >> 4, ln = lane & 15;
  const int n0 = blockIdx.x * 128;
  const int m0 = blockIdx.y * 64;
  const f16* ap = A + (size_t)(m0 + w*16 + ln)*K + q*8;
  const f16* bp = BT + (size_t)(n0 + ln)*K + q*8;
  f32x4 acc[8] = {};
  #pragma unroll 4
  for (int k = 0; k < K; k += 32){
    f16x8 af = *(const f16x8*)(ap + k);
    #pragma unroll
    for (int nt = 0; nt < 8; ++nt){
      f16x8 bf = *(const f16x8*)(bp + (size_t)nt*16*K + k);
      acc[nt] = __builtin_amdgcn_mfma_f32_16x16x32_f16(af, bf, acc[nt], 0, 0, 0);
    }
  }
  const int f32o = g_in_fp32;
  #pragma unroll
  for (int nt = 0; nt < 8; ++nt){
    const int col = n0 + nt*16 + ln;
    const float bv = bias[col];
    #pragma unroll
    for (int r = 0; r < 4; ++r){
      const int row = m0 + w*16 + q*4 + r;
      float v = acc[nt][r] + bv;
      if (MODE == 0){
        ((float*)C)[(size_t)row*N + col] = v;
      } else if (MODE == 1){
        ((f16*)C)[(size_t)row*N + col] = (f16)fmaxf(v, 0.f);
      } else {
        size_t idx = (col < 64) ? ((size_t)row*64 + col)
                                : (4194304UL + (size_t)row*64 + (size_t)(col - 64));
        if (f32o) ((float*)C)[idx] = v;
        else      ((u16*)C)[idx]   = f2bf(v);
      }
    }
  }
}
__global__ __launch_bounds__(256) void k_gemm_xw(){   gemm_body<0,KC >(g_xwin, g_cwxt, g_bb,  g_XW,   G4 ); }
__global__ __launch_bounds__(256) void k_gemm_mlp1(){ gemm_body<1,HID>(g_hseq, g_w1T,  g_b1f, g_tmp1, HID); }
__global__ __launch_bounds__(256) void k_gemm_mlp2(void* out){ gemm_body<2,HID>(g_tmp1, g_w2T, g_b2f, out, ZD2); }

// ---------------- persistent LSTM + heater ----------------
// LSTM core identical to R3 (32 WGs, gate-colocated, sentinel dataflow,
// selective re-poll). Two deltas:
//  (1) HEATER: 192 extra WGs run a pure-register VALU-FMA spin until g_done.
//      Purpose: keep ~88% of CUs busy so the DPM governor holds boost clocks
//      during the 1024-step serial chain (clock-floor experiment).
//  (2) XW(t+1) loads issued AFTER the gates, directly into the consumed xw
//      registers (no rotation copies) -> the first poll round's vmcnt(0) no
//      longer drains a cold HBM load; xw regs are tied into the poll waitcnt
//      dataflow for rule-#18 ordering.
__global__ __launch_bounds__(256, 1) void k_lstm(){
  __shared__ __align__(16) f16 whs[64*512];   // 64 KB
  const int g   = blockIdx.x;
  const int tid = threadIdx.x;

  if (g >= NWG){
    // -------- heater: 4 independent FMA chains, flag check ~1/1024cy --------
    float h0 = 1.0f + tid*1e-6f, h1 = 1.1f, h2 = 1.2f, h3 = 1.3f;
    const float m = 0.99999988f, a = 1e-7f;
    for (;;){
      #pragma unroll
      for (int it = 0; it < 128; ++it){
        h0 = __builtin_fmaf(h0, m, a);
        h1 = __builtin_fmaf(h1, m, a);
        h2 = __builtin_fmaf(h2, m, a);
        h3 = __builtin_fmaf(h3, m, a);
      }
      if (__hip_atomic_load(&g_done, __ATOMIC_RELAXED, __HIP_MEMORY_SCOPE_AGENT)) break;
    }
    asm volatile("" :: "v"(h0), "v"(h1), "v"(h2), "v"(h3));
    return;
  }

  const int w = tid >> 6, lane = tid & 63;
  const int q = lane >> 4, ln = lane & 15;
  const int jcol = g*16 + ln;                 // this thread's hidden col
  const int am   = w*16 + ln;                 // A-frag row (batch)

  // ---- stage Wh slice -> LDS, vectorized 16B, swizzled ----
  for (int idx = tid; idx < 64*64; idx += 256){
    int n = idx >> 6, k8 = (idx & 63) * 8;
    int zcol = (n >> 4)*HID + g*16 + (n & 15);
    *(f16x8*)&whs[(n << 9) | (k8 ^ ((n & 7) << 3))] =
        *(const f16x8*)&g_whT[(size_t)zcol*HID + k8];
  }
  __syncthreads();

  float c_st[4] = {0.f, 0.f, 0.f, 0.f};

  // ---- XW addressing: col = nt*512 + jcol, row = w*16+q*4+r ----
  size_t rowb[4];
  #pragma unroll
  for (int r = 0; r < 4; ++r) rowb[r] = (size_t)(w*16 + q*4 + r)*T_SEQ*G4;
  // pxw[r]   -> gate i (offset 0) / gate f (offset 2048) for row r
  // pxw[4+r] -> gate g (offset 0) / gate o (offset 2048) for row r
  u64 pxw[8];
  #pragma unroll
  for (int r = 0; r < 4; ++r){
    pxw[r]   = (u64)(const void*)&g_XW[rowb[r] + jcol];
    pxw[4+r] = (u64)(const void*)&g_XW[rowb[r] + 2*HID + jcol];
  }
  float xw[4][4];   // [gate][r], constant-indexed only

#define XW_ISSUE()                                                            \
  asm volatile(                                                               \
    "global_load_dword %0, %16, off\n"                                        \
    "global_load_dword %1, %16, off offset:2048\n"                            \
    "global_load_dword %2, %17, off\n"                                        \
    "global_load_dword %3, %17, off offset:2048\n"                            \
    "global_load_dword %4, %18, off\n"                                        \
    "global_load_dword %5, %18, off offset:2048\n"                            \
    "global_load_dword %6, %19, off\n"                                        \
    "global_load_dword %7, %19, off offset:2048\n"                            \
    "global_load_dword %8, %20, off\n"                                        \
    "global_load_dword %9, %20, off offset:2048\n"                            \
    "global_load_dword %10, %21, off\n"                                       \
    "global_load_dword %11, %21, off offset:2048\n"                           \
    "global_load_dword %12, %22, off\n"                                       \
    "global_load_dword %13, %22, off offset:2048\n"                           \
    "global_load_dword %14, %23, off\n"                                       \
    "global_load_dword %15, %23, off offset:2048\n"                           \
    : "=&v"(xw[0][0]), "=&v"(xw[1][0]), "=&v"(xw[2][0]), "=&v"(xw[3][0]),     \
      "=&v"(xw[0][1]), "=&v"(xw[1][1]), "=&v"(xw[2][1]), "=&v"(xw[3][1]),     \
      "=&v"(xw[0][2]), "=&v"(xw[1][2]), "=&v"(xw[2][2]), "=&v"(xw[3][2]),     \
      "=&v"(xw[0][3]), "=&v"(xw[1][3]), "=&v"(xw[2][3]), "=&v"(xw[3][3])      \
    : "v"(pxw[0]), "v"(pxw[4]), "v"(pxw[1]), "v"(pxw[5]),                     \
      "v"(pxw[2]), "v"(pxw[6]), "v"(pxw[3]), "v"(pxw[7])                      \
    : "memory")

  XW_ISSUE();   // prime t=0 (drained by first poll round)

  // per-lane byte address of this lane's h fragment in slot 0
  u64 addr = (u64)(const void*)(g_hstep + ((size_t)am)*128 + (size_t)q*2);

  #pragma unroll 1
  for (int t = 0; t < T_SEQ; ++t){
    u32x4 hr[16];
    // ---- issue all 16 h-slice loads (no wait) ----
#define ISSUE(KK, OFF)                                                         \
    asm volatile("global_load_dwordx4 %0, %1, off offset:" OFF " sc0 sc1"      \
                 : "=v"(hr[KK]) : "v"(addr) : "memory");
    ISSUE(0,"0")   ISSUE(1,"64")   ISSUE(2,"128")  ISSUE(3,"192")
    ISSUE(4,"256") ISSUE(5,"320")  ISSUE(6,"384")  ISSUE(7,"448")
    ISSUE(8,"512") ISSUE(9,"576")  ISSUE(10,"640") ISSUE(11,"704")
    ISSUE(12,"768")ISSUE(13,"832") ISSUE(14,"896") ISSUE(15,"960")

    // ---- poll: one vmcnt(0) per round, re-issue ONLY invalid slices.
    //      xw regs tied in so gate-reads can't be hoisted above the wait. ----
    u32 need = 0xFFFFu;
    for (;;){
      asm volatile("s_waitcnt vmcnt(0)"
        : "+v"(hr[0]),  "+v"(hr[1]),  "+v"(hr[2]),  "+v"(hr[3]),
          "+v"(hr[4]),  "+v"(hr[5]),  "+v"(hr[6]),  "+v"(hr[7]),
          "+v"(hr[8]),  "+v"(hr[9]),  "+v"(hr[10]), "+v"(hr[11]),
          "+v"(hr[12]), "+v"(hr[13]), "+v"(hr[14]), "+v"(hr[15]),
          "+v"(xw[0][0]), "+v"(xw[1][0]), "+v"(xw[2][0]), "+v"(xw[3][0]),
          "+v"(xw[0][1]), "+v"(xw[1][1]), "+v"(xw[2][1]), "+v"(xw[3][1]),
          "+v"(xw[0][2]), "+v"(xw[1][2]), "+v"(xw[2][2]), "+v"(xw[3][2]),
          "+v"(xw[0][3]), "+v"(xw[1][3]), "+v"(xw[2][3]), "+v"(xw[3][3])
        :: "memory");
      u32 nb = 0;
      #pragma unroll
      for (int kk = 0; kk < 16; ++kk)
        if (need & (1u<<kk))
          if (!__all(slice_ok(hr[kk]))) nb |= (1u<<kk);
      if (!nb) break;
      need = nb;
#define REISSUE(KK, OFF)                                                       \
      if (need & (1u<<KK))                                                     \
        asm volatile("global_load_dwordx4 %0, %1, off offset:" OFF " sc0 sc1"  \
                     : "=v"(hr[KK]) : "v"(addr) : "memory");
      REISSUE(0,"0")   REISSUE(1,"64")   REISSUE(2,"128")  REISSUE(3,"192")
      REISSUE(4,"256") REISSUE(5,"320")  REISSUE(6,"384")  REISSUE(7,"448")
      REISSUE(8,"512") REISSUE(9,"576")  REISSUE(10,"640") REISSUE(11,"704")
      REISSUE(12,"768")REISSUE(13,"832") REISSUE(14,"896") REISSUE(15,"960")
#undef REISSUE
    }
#undef ISSUE

    // ---- MFMA: 4 gate-chains x even/odd split (8 independent chains) ----
    f32x4 aA[4] = {}, aB[4] = {};
    #pragma unroll
    for (int kk = 0; kk < 16; ++kk){
      f16x8 af = __builtin_bit_cast(f16x8, hr[kk]);
      #pragma unroll
      for (int nt = 0; nt < 4; ++nt){
        f16x8 bf = *(const f16x8*)&whs[((nt*16 + ln) << 9) |
                                       ((kk*32 + q*8) ^ ((ln & 7) << 3))];
        if (kk & 1) aB[nt] = __builtin_amdgcn_mfma_f32_16x16x32_f16(af, bf, aB[nt], 0, 0, 0);
        else        aA[nt] = __builtin_amdgcn_mfma_f32_16x16x32_f16(af, bf, aA[nt], 0, 0, 0);
      }
    }

    // ---- gates (all lane-local) + immediate fire-and-forget publish ----
    f16 h16v[4];
    #pragma unroll
    for (int r = 0; r < 4; ++r){
      float zi = aA[0][r] + aB[0][r] + xw[0][r];
      float zf = aA[1][r] + aB[1][r] + xw[1][r];
      float zg = aA[2][r] + aB[2][r] + xw[2][r];
      float zo = aA[3][r] + aB[3][r] + xw[3][r];
      float iv = fsig(zi);
      float fv = fsig(zf);
      float gv = ftanh(zg);
      float ov = fsig(zo);
      float cn = fv*c_st[r] + iv*gv;
      c_st[r] = cn;
      float hvf = ov*ftanh(cn);
      f16 h16 = (f16)hvf;
      h16v[r] = h16;
      u32 me = (u32)__builtin_bit_cast(u16, h16);
      u32 p  = me | (((u32)__shfl_xor((int)me, 1, 64)) << 16);  // cols jcol,jcol+1
      if ((ln & 1) == 0){
        int m = w*16 + q*4 + r;
        __hip_atomic_store((u32*)g_hstep + ((size_t)(t+1)*NB + m)*256 + (jcol >> 1),
                           p, __ATOMIC_RELAXED, __HIP_MEMORY_SCOPE_AGENT);
      }
    }
    // hseq stores: consumed only by k_gemm_mlp1 (flushed at dispatch end)
    #pragma unroll
    for (int r = 0; r < 4; ++r){
      int m = w*16 + q*4 + r;
      g_hseq[((size_t)m*T_SEQ + t)*HID + jcol] = h16v[r];
    }
    // ---- advance XW pointers (clamp at last step) and issue t+1 loads
    //      directly into the xw registers (all reads above are done) ----
    const u64 step = (t < T_SEQ-1) ? (u64)G4*4 : 0;
    #pragma unroll
    for (int i = 0; i < 8; ++i) pxw[i] += step;
    XW_ISSUE();

    addr += (u64)NB*128*8;   // next ring slot (64KB)
  }
#undef XW_ISSUE

  // release the heaters
  if (g == 0 && tid == 0)
    __hip_atomic_store(&g_done, 1, __ATOMIC_RELAXED, __HIP_MEMORY_SCOPE_AGENT);
}

// ---------------- launch ----------------
extern "C" void kernel_launch(void* const* d_in, const int* in_sizes, int n_in,
                              void* d_out, int out_size, void* d_ws, size_t ws_size,
                              hipStream_t stream){
  const void* x      = d_in[0];
  const void* conv_w = d_in[1];
  const void* conv_b = d_in[2];
  const void* Wx     = d_in[3];
  const void* Wh     = d_in[4];
  const void* b      = d_in[5];
  const void* W1     = d_in[6];
  const void* b1     = d_in[7];
  const void* W2     = d_in[8];
  const void* b2     = d_in[9];
  (void)in_sizes; (void)n_in; (void)out_size; (void)d_ws; (void)ws_size;

  hipLaunchKernelGGL(k_probe,   dim3(1),        dim3(256), 0, stream, x);
  hipLaunchKernelGGL(k_init,    dim3(256),      dim3(256), 0, stream, b1, b2);
  hipLaunchKernelGGL(k_fill,    dim3(4096),     dim3(256), 0, stream);
  hipLaunchKernelGGL(k_combine, dim3(8, 385),   dim3(256), 0, stream, conv_w, conv_b, Wx, b);
  hipLaunchKernelGGL(k_trans_wh,dim3(4096),     dim3(256), 0, stream, Wh);
  hipLaunchKernelGGL(k_trans_w1,dim3(1024),     dim3(256), 0, stream, W1);
  hipLaunchKernelGGL(k_trans_w2,dim3(256),      dim3(256), 0, stream, W2);
  hipLaunchKernelGGL(k_xwin,    dim3(98304),    dim3(256), 0, stream, x);
  hipLaunchKernelGGL(k_gemm_xw, dim3(16, 1024), dim3(256), 0, stream);
  hipLaunchKernelGGL(k_lstm,    dim3(NWG+NHEAT), dim3(256), 0, stream);
  hipLaunchKernelGGL(k_gemm_mlp1, dim3(4, 1024), dim3(256), 0, stream);
  hipLaunchKernelGGL(k_gemm_mlp2, dim3(1, 1024), dim3(256), 0, stream, d_out);
}